// Round 3
// baseline (280.372 us; speedup 1.0000x reference)
//
#include <hip/hip_runtime.h>
#include <math.h>

#if __has_builtin(__builtin_amdgcn_exp2f)
#define EXP2F(x) __builtin_amdgcn_exp2f(x)
#else
#define EXP2F(x) exp2f(x)
#endif
#if __has_builtin(__builtin_amdgcn_rcpf)
#define RCPF(x) __builtin_amdgcn_rcpf(x)
#else
#define RCPF(x) (1.0f / (x))
#endif

namespace {
constexpr int IMG  = 1024;
constexpr int TW   = 64;     // tile 64x64 px, thread = 4x4 px, block 16x16 threads
constexpr int TH   = 64;
constexpr int LDSW = 68;     // stride == used cols; 68 mod 8 == 4 keeps row-groups 2-way only
constexpr int LDSH = 68;
constexpr float BIG   = 1e18f;               // OOB sentinel: exp2(-1e36) == 0 exactly
constexpr float LOG2E = 1.4426950408889634f;
// color pre-scale: u = x*s so per-tap arg = ls - (uc-us)^2 in ONE fma
constexpr float K1     = 0.84932180028801907f;  // sqrt(LOG2E/2)
constexpr float INV_K1 = 1.17741002251547466f;  // sqrt(2*ln2)
}

__global__ __launch_bounds__(256, 4)
void bilateral5x5(const float* __restrict__ x,
                  const float* __restrict__ p_sx,
                  const float* __restrict__ p_sy,
                  const float* __restrict__ p_sr,
                  float* __restrict__ out)
{
    __shared__ float tile[LDSH * LDSW];

    const int tx  = threadIdx.x;           // 0..15
    const int ty  = threadIdx.y;           // 0..15
    const int tid = ty * 16 + tx;

    const int gx0 = blockIdx.x * TW - 2;   // global col of LDS col 0
    const int gy0 = blockIdx.y * TH - 2;   // global row of LDS row 0
    const float* img = x + (size_t)blockIdx.z * (IMG * IMG);

    const float srv   = p_sr[0];
    const float s     = K1 / srv;
    const float inv_s = srv * INV_K1;

    // ---- stage 68x68 (pre-scaled), sentinel-filling OOB; coalesced linear idx ----
    for (int idx = tid; idx < LDSH * LDSW; idx += 256) {
        const int r  = idx / LDSW;         // magic-mul
        const int c  = idx - r * LDSW;
        const int gx = gx0 + c;
        const int gy = gy0 + r;
        float v = BIG;
        if ((unsigned)gx < (unsigned)IMG && (unsigned)gy < (unsigned)IMG)
            v = img[gy * IMG + gx] * s;
        tile[idx] = v;
    }
    __syncthreads();

    // ---- spatial log2-weights: row offsets use sigma_x, col offsets sigma_y (ref semantics) ----
    const float sxv = p_sx[0], syv = p_sy[0];
    const float ar = -LOG2E / (2.0f * sxv * sxv);
    const float ac = -LOG2E / (2.0f * syv * syv);
    float ls9[3][3];
    #pragma unroll
    for (int i = 0; i < 3; ++i)
        #pragma unroll
        for (int j = 0; j < 3; ++j)
            ls9[i][j] = ar * (float)(i * i) + ac * (float)(j * j);

    const float4* t4 = reinterpret_cast<const float4*>(tile);  // row stride 17 units
    const int r0 = ty * 4;                 // LDS row of window row 0

    // ---- own 4x4 pixels; init accumulators with free center tap (w == 1) ----
    float c[4][4], num[4][4], den[4][4];
    #pragma unroll
    for (int r = 0; r < 4; ++r) {
        const int lr = r0 + 2 + r;
        const float4 a = t4[lr * 17 + tx];
        const float4 b = t4[lr * 17 + tx + 1];
        c[r][0] = a.z; c[r][1] = a.w; c[r][2] = b.x; c[r][3] = b.y;
        #pragma unroll
        for (int j = 0; j < 4; ++j) { num[r][j] = c[r][j]; den[r][j] = 1.0f; }
    }

    // ---- 8 window rows; shared pairs computed once, accumulated into both endpoints ----
    #pragma unroll
    for (int wr = 0; wr < 8; ++wr) {
        const int lr = r0 + wr;
        const float4 a = t4[lr * 17 + tx];
        const float4 b = t4[lr * 17 + tx + 1];
        const float v[8] = {a.x, a.y, a.z, a.w, b.x, b.y, b.z, b.w};
        #pragma unroll
        for (int orow = 0; orow < 4; ++orow) {
            const int dy = wr - 2 - orow;
            if (dy < -2 || dy > 2) continue;
            const int ady = dy < 0 ? -dy : dy;
            #pragma unroll
            for (int ocol = 0; ocol < 4; ++ocol) {
                #pragma unroll
                for (int dx = -2; dx <= 2; ++dx) {
                    if (dy == 0 && dx == 0) continue;             // center: already in init
                    const int wc  = ocol + 2 + dx;
                    const int adx = dx < 0 ? -dx : dx;
                    const bool qown = (wr >= 2 && wr <= 5 && wc >= 2 && wc <= 5);
                    if (qown && (dy < 0 || (dy == 0 && dx < 0))) continue;  // pair counted once
                    const float u = v[wc];
                    const float d = c[orow][ocol] - u;
                    const float w = EXP2F(fmaf(-d, d, ls9[ady][adx]));
                    num[orow][ocol] = fmaf(w, u, num[orow][ocol]);
                    den[orow][ocol] += w;
                    if (qown) {                                   // symmetric partner
                        const int qr = wr - 2, qc = wc - 2;
                        num[qr][qc] = fmaf(w, c[orow][ocol], num[qr][qc]);
                        den[qr][qc] += w;
                    }
                }
            }
        }
    }

    // ---- write 4 rows of float4 ----
    float* outimg = out + (size_t)blockIdx.z * (IMG * IMG);
    const int gxo = blockIdx.x * TW + tx * 4;
    #pragma unroll
    for (int r = 0; r < 4; ++r) {
        const int gy = blockIdx.y * TH + ty * 4 + r;
        float4 o;
        o.x = num[r][0] * RCPF(den[r][0]) * inv_s;
        o.y = num[r][1] * RCPF(den[r][1]) * inv_s;
        o.z = num[r][2] * RCPF(den[r][2]) * inv_s;
        o.w = num[r][3] * RCPF(den[r][3]) * inv_s;
        *reinterpret_cast<float4*>(&outimg[gy * IMG + gxo]) = o;
    }
}

extern "C" void kernel_launch(void* const* d_in, const int* in_sizes, int n_in,
                              void* d_out, int out_size, void* d_ws, size_t ws_size,
                              hipStream_t stream) {
    const float* x  = (const float*)d_in[0];
    const float* sx = (const float*)d_in[1];
    const float* sy = (const float*)d_in[2];
    // d_in[3] = sigma_z: dz == 0 always -> term contributes exactly 0, unused
    const float* sr = (const float*)d_in[4];
    float* out = (float*)d_out;

    const int B = in_sizes[0] / (IMG * IMG);   // 16
    dim3 grid(IMG / TW, IMG / TH, B);          // (16, 16, 16)
    dim3 block(16, 16, 1);
    bilateral5x5<<<grid, block, 0, stream>>>(x, sx, sy, sr, out);
}

// Round 4
// 216.488 us; speedup vs baseline: 1.2951x; 1.2951x over previous
//
#include <hip/hip_runtime.h>
#include <math.h>

#if __has_builtin(__builtin_amdgcn_exp2f)
#define EXP2F(x) __builtin_amdgcn_exp2f(x)
#else
#define EXP2F(x) exp2f(x)
#endif
#if __has_builtin(__builtin_amdgcn_rcpf)
#define RCPF(x) __builtin_amdgcn_rcpf(x)
#else
#define RCPF(x) (1.0f / (x))
#endif

namespace {
constexpr int IMG  = 1024;
constexpr int TW   = 64;     // tile 64x64 px, thread = 4x4 px, block 16x16 threads
constexpr int TH   = 64;
constexpr int LDSW = 68;     // == used cols; float4 row stride = 17
constexpr int LDSH = 68;
constexpr float BIG   = 1e18f;               // OOB sentinel: exp2(-1e36) == 0 exactly
constexpr float LOG2E = 1.4426950408889634f;
constexpr float K1     = 0.84932180028801907f;  // sqrt(LOG2E/2)   (color pre-scale)
constexpr float INV_K1 = 1.17741002251547466f;  // sqrt(2*ln2)
}

struct Acc {
    float c[4][4];    // own pixels (scaled space)
    float num[4][4];
    float den[4][4];
};

// One output-row slice of one window row. WR, OROW are template params so
// dy/ady and all pair indices are compile-time constants (no scratch demotion).
template<int WR, int OROW>
__device__ __forceinline__ void taps_orow(const float (&v)[8], Acc& A,
                                          const float (&ls9)[3][3])
{
    constexpr int DY = WR - 2 - OROW;
    if constexpr (DY >= -2 && DY <= 2) {
        constexpr int ADY = DY < 0 ? -DY : DY;
        #pragma unroll
        for (int ocol = 0; ocol < 4; ++ocol) {
            #pragma unroll
            for (int dx = -2; dx <= 2; ++dx) {
                if (DY == 0 && dx == 0) continue;              // center handled at init
                const int wc  = ocol + 2 + dx;
                const int adx = dx < 0 ? -dx : dx;
                const bool qown = (WR >= 2 && WR <= 5 && wc >= 2 && wc <= 5);
                if (qown && (DY < 0 || (DY == 0 && dx < 0))) continue;  // each pair once
                const float u = v[wc];
                const float d = A.c[OROW][ocol] - u;
                const float w = EXP2F(fmaf(-d, d, ls9[ADY][adx]));
                A.num[OROW][ocol] = fmaf(w, u, A.num[OROW][ocol]);
                A.den[OROW][ocol] += w;
                if (qown) {                                    // symmetric partner
                    const int qr = WR - 2, qc = wc - 2;
                    A.num[qr][qc] = fmaf(w, A.c[OROW][ocol], A.num[qr][qc]);
                    A.den[qr][qc] += w;
                }
            }
        }
    }
}

template<int WR>
__device__ __forceinline__ void window_row(const float4* __restrict__ t4, int rowbase,
                                           int tx, Acc& A, const float (&ls9)[3][3])
{
    const float4 a = t4[(rowbase + WR) * 17 + tx];
    const float4 b = t4[(rowbase + WR) * 17 + tx + 1];
    const float v[8] = {a.x, a.y, a.z, a.w, b.x, b.y, b.z, b.w};
    taps_orow<WR, 0>(v, A, ls9);
    taps_orow<WR, 1>(v, A, ls9);
    taps_orow<WR, 2>(v, A, ls9);
    taps_orow<WR, 3>(v, A, ls9);
}

__global__ __launch_bounds__(256)
void bilateral5x5(const float* __restrict__ x,
                  const float* __restrict__ p_sx,
                  const float* __restrict__ p_sy,
                  const float* __restrict__ p_sr,
                  float* __restrict__ out)
{
    __shared__ float tile[LDSH * LDSW];

    const int tx  = threadIdx.x;           // 0..15
    const int ty  = threadIdx.y;           // 0..15
    const int tid = ty * 16 + tx;

    const int gx0 = blockIdx.x * TW - 2;
    const int gy0 = blockIdx.y * TH - 2;
    const float* img = x + (size_t)blockIdx.z * (IMG * IMG);

    const float srv   = p_sr[0];
    const float s     = K1 / srv;
    const float inv_s = srv * INV_K1;

    // ---- stage 68x68 (pre-scaled), sentinel-filling OOB ----
    for (int idx = tid; idx < LDSH * LDSW; idx += 256) {
        const int r  = idx / LDSW;
        const int c  = idx - r * LDSW;
        const int gx = gx0 + c;
        const int gy = gy0 + r;
        float v = BIG;
        if ((unsigned)gx < (unsigned)IMG && (unsigned)gy < (unsigned)IMG)
            v = img[gy * IMG + gx] * s;
        tile[idx] = v;
    }
    __syncthreads();

    // ---- spatial log2-weights (row offset -> sigma_x, col offset -> sigma_y) ----
    const float sxv = p_sx[0], syv = p_sy[0];
    const float ar = -LOG2E / (2.0f * sxv * sxv);
    const float ac = -LOG2E / (2.0f * syv * syv);
    float ls9[3][3];
    #pragma unroll
    for (int i = 0; i < 3; ++i)
        #pragma unroll
        for (int j = 0; j < 3; ++j)
            ls9[i][j] = ar * (float)(i * i) + ac * (float)(j * j);

    const float4* t4 = reinterpret_cast<const float4*>(tile);
    const int rowbase = ty * 4;            // LDS row of window row 0

    // ---- init accumulators with free center tap (w == 1) ----
    Acc A;
    #pragma unroll
    for (int r = 0; r < 4; ++r) {
        const int lr = rowbase + 2 + r;
        const float4 a = t4[lr * 17 + tx];
        const float4 b = t4[lr * 17 + tx + 1];
        A.c[r][0] = a.z; A.c[r][1] = a.w; A.c[r][2] = b.x; A.c[r][3] = b.y;
        #pragma unroll
        for (int j = 0; j < 4; ++j) { A.num[r][j] = A.c[r][j]; A.den[r][j] = 1.0f; }
    }

    // ---- 8 window rows, explicit template instantiation (guaranteed unroll) ----
    window_row<0>(t4, rowbase, tx, A, ls9);
    window_row<1>(t4, rowbase, tx, A, ls9);
    window_row<2>(t4, rowbase, tx, A, ls9);
    window_row<3>(t4, rowbase, tx, A, ls9);
    window_row<4>(t4, rowbase, tx, A, ls9);
    window_row<5>(t4, rowbase, tx, A, ls9);
    window_row<6>(t4, rowbase, tx, A, ls9);
    window_row<7>(t4, rowbase, tx, A, ls9);

    // ---- write 4 rows of float4 ----
    float* outimg = out + (size_t)blockIdx.z * (IMG * IMG);
    const int gxo = blockIdx.x * TW + tx * 4;
    #pragma unroll
    for (int r = 0; r < 4; ++r) {
        const int gy = blockIdx.y * TH + ty * 4 + r;
        float4 o;
        o.x = A.num[r][0] * RCPF(A.den[r][0]) * inv_s;
        o.y = A.num[r][1] * RCPF(A.den[r][1]) * inv_s;
        o.z = A.num[r][2] * RCPF(A.den[r][2]) * inv_s;
        o.w = A.num[r][3] * RCPF(A.den[r][3]) * inv_s;
        *reinterpret_cast<float4*>(&outimg[gy * IMG + gxo]) = o;
    }
}

extern "C" void kernel_launch(void* const* d_in, const int* in_sizes, int n_in,
                              void* d_out, int out_size, void* d_ws, size_t ws_size,
                              hipStream_t stream) {
    const float* x  = (const float*)d_in[0];
    const float* sx = (const float*)d_in[1];
    const float* sy = (const float*)d_in[2];
    // d_in[3] = sigma_z: dz == 0 always -> contributes exactly 0, unused
    const float* sr = (const float*)d_in[4];
    float* out = (float*)d_out;

    const int B = in_sizes[0] / (IMG * IMG);   // 16
    dim3 grid(IMG / TW, IMG / TH, B);          // (16, 16, 16)
    dim3 block(16, 16, 1);
    bilateral5x5<<<grid, block, 0, stream>>>(x, sx, sy, sr, out);
}

// Round 5
// 197.637 us; speedup vs baseline: 1.4186x; 1.0954x over previous
//
#include <hip/hip_runtime.h>
#include <math.h>

#if __has_builtin(__builtin_amdgcn_exp2f)
#define EXP2F(x) __builtin_amdgcn_exp2f(x)
#else
#define EXP2F(x) exp2f(x)
#endif
#if __has_builtin(__builtin_amdgcn_rcpf)
#define RCPF(x) __builtin_amdgcn_rcpf(x)
#else
#define RCPF(x) (1.0f / (x))
#endif

namespace {
constexpr int IMG  = 1024;
constexpr int TW   = 64;     // tile 64 cols x 32 rows; thread = 4 cols x 2 rows
constexpr int TH   = 32;
constexpr int LDSW = 68;     // float4 row stride = 17
constexpr int LDSH = 36;
constexpr float BIG   = 1e18f;               // OOB sentinel: exp2(-1e36) == 0 exactly
constexpr float LOG2E = 1.4426950408889634f;
constexpr float K1     = 0.84932180028801907f;  // sqrt(LOG2E/2)  (color pre-scale)
constexpr float INV_K1 = 1.17741002251547466f;  // sqrt(2*ln2)
}

struct Acc {
    float c[2][4];     // own pixels (scaled space)
    float num[2][4];
    float den[2][4];
};

// One own-row slice of one window row. All indices compile-time (no scratch).
template<int WR, int OROW>
__device__ __forceinline__ void taps_orow(const float (&v)[8], Acc& A,
                                          const float (&ls9)[3][3])
{
    constexpr int DY = WR - 2 - OROW;
    if constexpr (DY >= -2 && DY <= 2) {
        constexpr int ADY = DY < 0 ? -DY : DY;
        #pragma unroll
        for (int ocol = 0; ocol < 4; ++ocol) {
            #pragma unroll
            for (int dx = -2; dx <= 2; ++dx) {
                if (DY == 0 && dx == 0) continue;              // center handled at init
                const int wc  = ocol + 2 + dx;
                const int adx = dx < 0 ? -dx : dx;
                // partner-ownership: window px is one of our own 2x4 block
                const bool qown = (WR >= 2 && WR <= 3 && wc >= 2 && wc <= 5);
                if (qown && (DY < 0 || (DY == 0 && dx < 0))) continue;  // each pair once
                const float u = v[wc];
                const float d = A.c[OROW][ocol] - u;
                const float w = EXP2F(fmaf(-d, d, ls9[ADY][adx]));
                A.num[OROW][ocol] = fmaf(w, u, A.num[OROW][ocol]);
                A.den[OROW][ocol] += w;
                if (qown) {                                    // symmetric partner (exact)
                    const int qr = WR - 2, qc = wc - 2;
                    A.num[qr][qc] = fmaf(w, A.c[OROW][ocol], A.num[qr][qc]);
                    A.den[qr][qc] += w;
                }
            }
        }
    }
}

template<int WR>
__device__ __forceinline__ void window_row(const float4* __restrict__ t4, int rowbase,
                                           int tx, Acc& A, const float (&ls9)[3][3])
{
    const float4 a = t4[(rowbase + WR) * 17 + tx];
    const float4 b = t4[(rowbase + WR) * 17 + tx + 1];
    const float v[8] = {a.x, a.y, a.z, a.w, b.x, b.y, b.z, b.w};
    taps_orow<WR, 0>(v, A, ls9);
    taps_orow<WR, 1>(v, A, ls9);
}

__global__ __launch_bounds__(256)
void bilateral5x5(const float* __restrict__ x,
                  const float* __restrict__ p_sx,
                  const float* __restrict__ p_sy,
                  const float* __restrict__ p_sr,
                  float* __restrict__ out)
{
    __shared__ float tile[LDSH * LDSW];

    const int tx  = threadIdx.x;           // 0..15
    const int ty  = threadIdx.y;           // 0..15
    const int tid = ty * 16 + tx;

    const int gx0 = blockIdx.x * TW - 2;
    const int gy0 = blockIdx.y * TH - 2;
    const float* img = x + (size_t)blockIdx.z * (IMG * IMG);

    const float srv   = p_sr[0];
    const float s     = K1 / srv;
    const float inv_s = srv * INV_K1;

    // ---- stage 68x36 (pre-scaled), sentinel-filling OOB ----
    for (int idx = tid; idx < LDSH * LDSW; idx += 256) {
        const int r  = idx / LDSW;         // magic-mul
        const int c  = idx - r * LDSW;
        const int gx = gx0 + c;
        const int gy = gy0 + r;
        float v = BIG;
        if ((unsigned)gx < (unsigned)IMG && (unsigned)gy < (unsigned)IMG)
            v = img[gy * IMG + gx] * s;
        tile[idx] = v;
    }
    __syncthreads();

    // ---- spatial log2-weights (row offset -> sigma_x, col offset -> sigma_y) ----
    const float sxv = p_sx[0], syv = p_sy[0];
    const float ar = -LOG2E / (2.0f * sxv * sxv);
    const float ac = -LOG2E / (2.0f * syv * syv);
    float ls9[3][3];
    #pragma unroll
    for (int i = 0; i < 3; ++i)
        #pragma unroll
        for (int j = 0; j < 3; ++j)
            ls9[i][j] = ar * (float)(i * i) + ac * (float)(j * j);

    const float4* t4 = reinterpret_cast<const float4*>(tile);
    const int rowbase = ty * 2;            // LDS row of window row 0

    // ---- init accumulators with free center tap (w == 1) ----
    Acc A;
    #pragma unroll
    for (int r = 0; r < 2; ++r) {
        const int lr = rowbase + 2 + r;
        const float4 a = t4[lr * 17 + tx];
        const float4 b = t4[lr * 17 + tx + 1];
        A.c[r][0] = a.z; A.c[r][1] = a.w; A.c[r][2] = b.x; A.c[r][3] = b.y;
        #pragma unroll
        for (int j = 0; j < 4; ++j) { A.num[r][j] = A.c[r][j]; A.den[r][j] = 1.0f; }
    }

    // ---- 6 window rows, explicit instantiation (guaranteed static unroll) ----
    window_row<0>(t4, rowbase, tx, A, ls9);
    window_row<1>(t4, rowbase, tx, A, ls9);
    window_row<2>(t4, rowbase, tx, A, ls9);
    window_row<3>(t4, rowbase, tx, A, ls9);
    window_row<4>(t4, rowbase, tx, A, ls9);
    window_row<5>(t4, rowbase, tx, A, ls9);

    // ---- write 2 rows of float4 ----
    float* outimg = out + (size_t)blockIdx.z * (IMG * IMG);
    const int gxo = blockIdx.x * TW + tx * 4;
    #pragma unroll
    for (int r = 0; r < 2; ++r) {
        const int gy = blockIdx.y * TH + ty * 2 + r;
        float4 o;
        o.x = A.num[r][0] * RCPF(A.den[r][0]) * inv_s;
        o.y = A.num[r][1] * RCPF(A.den[r][1]) * inv_s;
        o.z = A.num[r][2] * RCPF(A.den[r][2]) * inv_s;
        o.w = A.num[r][3] * RCPF(A.den[r][3]) * inv_s;
        *reinterpret_cast<float4*>(&outimg[gy * IMG + gxo]) = o;
    }
}

extern "C" void kernel_launch(void* const* d_in, const int* in_sizes, int n_in,
                              void* d_out, int out_size, void* d_ws, size_t ws_size,
                              hipStream_t stream) {
    const float* x  = (const float*)d_in[0];
    const float* sx = (const float*)d_in[1];
    const float* sy = (const float*)d_in[2];
    // d_in[3] = sigma_z: dz == 0 always -> contributes exactly 0, unused
    const float* sr = (const float*)d_in[4];
    float* out = (float*)d_out;

    const int B = in_sizes[0] / (IMG * IMG);   // 16
    dim3 grid(IMG / TW, IMG / TH, B);          // (16, 32, 16)
    dim3 block(16, 16, 1);
    bilateral5x5<<<grid, block, 0, stream>>>(x, sx, sy, sr, out);
}